// Round 11
// baseline (837.202 us; speedup 1.0000x reference)
//
#include <hip/hip_runtime.h>

#define NB 512
#define NN 200
#define ND 256
#define TI 20
#define DC 16
#define NTILE 10           // NN / TI
#define NEG_INF -9.0e15f
#define SLOPE 0.2f

#define HJ_STRIDE 204      // floats; transposed hj rows (16B-aligned)
#define KSTR 20            // floats per k-slot (16 d + pad, 80B: 16B-aligned)
#define RSTR 80            // floats per i-row (4 k-slots)
#define P1_HJ (DC * HJ_STRIDE)          // 3264 floats
#define P1_W  (TI * RSTR)               // 1600 floats
#define POOLF (P1_HJ + P1_W)            // 4864 floats = 19456 B (>= sS 4000 floats)

__global__ __launch_bounds__(256, 4)   // 128-VGPR cap, 4 blocks/CU target
void gat_sel4_kernel(const float* __restrict__ h,
                     const int*   __restrict__ adj,
                     const float* __restrict__ a0,
                     const float* __restrict__ a1,
                     const float* __restrict__ a2,
                     const float* __restrict__ a3,
                     float* __restrict__ out)
{
    __shared__ __align__(16) float pool[POOLF];
    float (*sHjT)[HJ_STRIDE] = (float (*)[HJ_STRIDE])pool;   // [DC][204]
    float* sW2               = pool + P1_HJ;                 // [20 rows][4 k][20]
    float (*sS)[NN]          = (float (*)[NN])pool;          // [TI][200]

    const int tid = threadIdx.x;
    const int b   = blockIdx.x / NTILE;
    const int it  = blockIdx.x % NTILE;
    const int i0  = it * TI;

    const int ig = tid / 50;            // 0..4 active, 5 => inactive (tid 250-255)
    const int jg = tid % 50;            // j-quad index: j = 4*jg + jj
    const bool active = (ig < 5);

    const float* hb = h + (size_t)b * NN * ND;

    // ---- adj -> 16 gather offsets (named scalars) + 16-bit validity mask ----
    unsigned int vmask = 0;
    int o00, o01, o02, o03, o10, o11, o12, o13,
        o20, o21, o22, o23, o30, o31, o32, o33;
    {
        int kk[4][4];
        #pragma unroll
        for (int ii = 0; ii < 4; ++ii)
            #pragma unroll
            for (int jj = 0; jj < 4; ++jj)
                kk[ii][jj] = -1;
        if (active) {
            #pragma unroll
            for (int ii = 0; ii < 4; ++ii) {
                const int i = i0 + ig * 4 + ii;
                const int4 a4 = *(const int4*)(adj + ((size_t)b * NN + i) * NN + 4 * jg);
                kk[ii][0] = a4.x - 1;
                kk[ii][1] = a4.y - 1;
                kk[ii][2] = a4.z - 1;
                kk[ii][3] = a4.w - 1;
            }
        }
        #pragma unroll
        for (int ii = 0; ii < 4; ++ii)
            #pragma unroll
            for (int jj = 0; jj < 4; ++jj)
                if (kk[ii][jj] >= 0) vmask |= (1u << (ii * 4 + jj));
#define MKOFF(II, JJ) \
        o##II##JJ = (ig * 4 + II) * RSTR + ((kk[II][JJ] >= 0) ? kk[II][JJ] : 0) * KSTR;
        MKOFF(0,0) MKOFF(0,1) MKOFF(0,2) MKOFF(0,3)
        MKOFF(1,0) MKOFF(1,1) MKOFF(1,2) MKOFF(1,3)
        MKOFF(2,0) MKOFF(2,1) MKOFF(2,2) MKOFF(2,3)
        MKOFF(3,0) MKOFF(3,1) MKOFF(3,2) MKOFF(3,3)
#undef MKOFF
    }   // kk dies here

    float acc[4][4];
    #pragma unroll
    for (int ii = 0; ii < 4; ++ii)
        #pragma unroll
        for (int jj = 0; jj < 4; ++jj)
            acc[ii][jj] = 0.0f;

    // ---- score phase: loop d in chunks of DC=16 ----
    for (int dt = 0; dt < ND; dt += DC) {
        // stage h_j transposed, and w = h_i*a_k as [row][k][16+pad]
        {
            const int row = tid >> 2;            // 0..63
            const int c4  = (tid & 3) * 4;       // 0,4,8,12
            for (int j = row; j < NN; j += 64) {
                const float4 v = *(const float4*)(hb + j * ND + dt + c4);
                sHjT[c4 + 0][j] = v.x;
                sHjT[c4 + 1][j] = v.y;
                sHjT[c4 + 2][j] = v.z;
                sHjT[c4 + 3][j] = v.w;
            }
            if (row < TI) {
                const float4 hv  = *(const float4*)(hb + (i0 + row) * ND + dt + c4);
                const float4 va0 = *(const float4*)(a0 + dt + c4);
                const float4 va1 = *(const float4*)(a1 + dt + c4);
                const float4 va2 = *(const float4*)(a2 + dt + c4);
                const float4 va3 = *(const float4*)(a3 + dt + c4);
                float4 w;
                w.x = hv.x * va0.x; w.y = hv.y * va0.y; w.z = hv.z * va0.z; w.w = hv.w * va0.w;
                *(float4*)(sW2 + row * RSTR + 0 * KSTR + c4) = w;
                w.x = hv.x * va1.x; w.y = hv.y * va1.y; w.z = hv.z * va1.z; w.w = hv.w * va1.w;
                *(float4*)(sW2 + row * RSTR + 1 * KSTR + c4) = w;
                w.x = hv.x * va2.x; w.y = hv.y * va2.y; w.z = hv.z * va2.z; w.w = hv.w * va2.w;
                *(float4*)(sW2 + row * RSTR + 2 * KSTR + c4) = w;
                w.x = hv.x * va3.x; w.y = hv.y * va3.y; w.z = hv.z * va3.z; w.w = hv.w * va3.w;
                *(float4*)(sW2 + row * RSTR + 3 * KSTR + c4) = w;
            }
        }
        __syncthreads();

        if (active) {
            #pragma unroll
            for (int dd4 = 0; dd4 < DC; dd4 += 4) {
                float hjv[4][4];                       // [e][jj]
                #pragma unroll
                for (int e = 0; e < 4; ++e) {
                    const float4 v = *(const float4*)&sHjT[dd4 + e][4 * jg];  // b128
                    hjv[e][0] = v.x; hjv[e][1] = v.y; hjv[e][2] = v.z; hjv[e][3] = v.w;
                }
#define GSTEP(II, JJ) { \
                const float4 w4 = *(const float4*)(sW2 + o##II##JJ + dd4); \
                float a = acc[II][JJ]; \
                a += w4.x * hjv[0][JJ]; \
                a += w4.y * hjv[1][JJ]; \
                a += w4.z * hjv[2][JJ]; \
                a += w4.w * hjv[3][JJ]; \
                acc[II][JJ] = a; }
                GSTEP(0,0) GSTEP(0,1) GSTEP(0,2) GSTEP(0,3)
                GSTEP(1,0) GSTEP(1,1) GSTEP(1,2) GSTEP(1,3)
                GSTEP(2,0) GSTEP(2,1) GSTEP(2,2) GSTEP(2,3)
                GSTEP(3,0) GSTEP(3,1) GSTEP(3,2) GSTEP(3,3)
#undef GSTEP
            }
        }
        __syncthreads();
    }
    // phase-1 LDS dead from here; sS takes over the pool (barrier above).

    // ---- leaky-relu + mask, write scores to LDS (float4) ----
    if (active) {
        #pragma unroll
        for (int ii = 0; ii < 4; ++ii) {
            float tmp[4];
            #pragma unroll
            for (int jj = 0; jj < 4; ++jj) {
                float s = acc[ii][jj];
                s = (s >= 0.0f) ? s : SLOPE * s;
                tmp[jj] = ((vmask >> (ii * 4 + jj)) & 1u) ? s : NEG_INF;
            }
            float4 sv;
            sv.x = tmp[0]; sv.y = tmp[1]; sv.z = tmp[2]; sv.w = tmp[3];
            *(float4*)&sS[ig * 4 + ii][4 * jg] = sv;
        }
    }
    __syncthreads();

    // ---- row softmax: 4 waves x 5 rows, shuffle reduce over 64 lanes ----
    const int wv   = tid >> 6;   // 0..3
    const int lane = tid & 63;
    #pragma unroll
    for (int r = 0; r < 5; ++r) {
        const int row = wv * 5 + r;
        const float v0 = sS[row][lane];
        const float v1 = sS[row][lane + 64];
        const float v2 = sS[row][lane + 128];
        const float v3 = (lane < 8) ? sS[row][lane + 192] : NEG_INF;
        float m = fmaxf(fmaxf(v0, v1), fmaxf(v2, v3));
        #pragma unroll
        for (int off = 32; off > 0; off >>= 1)
            m = fmaxf(m, __shfl_xor(m, off, 64));
        const float p0 = __expf(v0 - m);
        const float p1 = __expf(v1 - m);
        const float p2 = __expf(v2 - m);
        const float p3 = (lane < 8) ? __expf(v3 - m) : 0.0f;
        float l = p0 + p1 + p2 + p3;
        #pragma unroll
        for (int off = 32; off > 0; off >>= 1)
            l += __shfl_xor(l, off, 64);
        const float inv = 1.0f / l;
        sS[row][lane]       = p0 * inv;
        sS[row][lane + 64]  = p1 * inv;
        sS[row][lane + 128] = p2 * inv;
        if (lane < 8) sS[row][lane + 192] = p3 * inv;
    }
    __syncthreads();

    // ---- PV: out[i][:] = sum_j alpha[i][j] * h[j][:]  (wave = 5 rows, j-quads) ----
    float o[5][4];
    #pragma unroll
    for (int r = 0; r < 5; ++r)
        #pragma unroll
        for (int c = 0; c < 4; ++c)
            o[r][c] = 0.0f;

    const int dcol = lane * 4;
    #pragma unroll 2
    for (int j4 = 0; j4 < NN / 4; ++j4) {
        float alr[5][4];
        #pragma unroll
        for (int r = 0; r < 5; ++r) {
            const float4 a4 = *(const float4*)&sS[wv * 5 + r][4 * j4]; // b128 bcast
            alr[r][0] = a4.x; alr[r][1] = a4.y; alr[r][2] = a4.z; alr[r][3] = a4.w;
        }
        #pragma unroll
        for (int q = 0; q < 4; ++q) {
            const float4 hv = *(const float4*)(hb + (size_t)(4 * j4 + q) * ND + dcol);
            #pragma unroll
            for (int r = 0; r < 5; ++r) {
                o[r][0] += alr[r][q] * hv.x;
                o[r][1] += alr[r][q] * hv.y;
                o[r][2] += alr[r][q] * hv.z;
                o[r][3] += alr[r][q] * hv.w;
            }
        }
    }

    #pragma unroll
    for (int r = 0; r < 5; ++r) {
        const int i = i0 + wv * 5 + r;
        float4 v;
        v.x = o[r][0]; v.y = o[r][1]; v.z = o[r][2]; v.w = o[r][3];
        *(float4*)(out + ((size_t)b * NN + i) * ND + dcol) = v;
    }
}

extern "C" void kernel_launch(void* const* d_in, const int* in_sizes, int n_in,
                              void* d_out, int out_size, void* d_ws, size_t ws_size,
                              hipStream_t stream) {
    const float* h   = (const float*)d_in[0];
    const int*   adj = (const int*)d_in[1];
    const float* a0  = (const float*)d_in[2];
    const float* a1  = (const float*)d_in[3];
    const float* a2  = (const float*)d_in[4];
    const float* a3  = (const float*)d_in[5];
    float* out = (float*)d_out;

    dim3 grid(NB * NTILE);   // 5120 blocks
    dim3 block(256);
    gat_sel4_kernel<<<grid, block, 0, stream>>>(h, adj, a0, a1, a2, a3, out);
}

// Round 12
// 685.910 us; speedup vs baseline: 1.2206x; 1.2206x over previous
//
#include <hip/hip_runtime.h>

#define NB 512
#define NN 200
#define ND 256
#define TI 20
#define DC 16
#define NTILE 10           // NN / TI
#define NEG_INF -9.0e15f
#define SLOPE 0.2f

#define HJ_STRIDE 204      // floats; 816B rows: b128-aligned reads, 2-way writes @256thr
#define WI_STRIDE 28       // floats; 112B rows: b128-aligned reads, 2-way writes
#define P1_HJ (DC * HJ_STRIDE)          // 3264 floats
#define P1_W  (4 * DC * WI_STRIDE)      // 1792 floats
#define POOLF (P1_HJ + P1_W)            // 5056 floats = 20224 B (>= sS 4000 floats)

__global__ __launch_bounds__(256, 4)
void gat_w4_kernel(const float* __restrict__ h,
                   const int*   __restrict__ adj,
                   const float* __restrict__ a0,
                   const float* __restrict__ a1,
                   const float* __restrict__ a2,
                   const float* __restrict__ a3,
                   float* __restrict__ out)
{
    // One all-float pool; phase-1 (sHjT,sW) and phase-2 (sS) lifetimes are
    // disjoint (barrier-separated).
    __shared__ __align__(16) float pool[POOLF];
    float (*sHjT)[HJ_STRIDE]   = (float (*)[HJ_STRIDE])pool;               // [DC][204]
    float (*sW)[DC][WI_STRIDE] = (float (*)[DC][WI_STRIDE])(pool + P1_HJ); // [4][DC][28]
    float (*sS)[NN]            = (float (*)[NN])pool;                      // [TI][200]

    const int tid = threadIdx.x;
    const int b   = blockIdx.x / NTILE;
    const int it  = blockIdx.x % NTILE;
    const int i0  = it * TI;

    // ---- score-phase mapping: 5 i-groups x 50 j-quads (250 active) ----
    const int ig = tid / 50;            // 0..4 active; 5 => inactive (tid 250-255)
    const int jg = tid % 50;            // j-quad index: j = 4*jg + jj
    const bool active = (ig < 5);

    const float* hb = h + (size_t)b * NN * ND;

    // read adj selections once (vector int4); k = adj-1 in [0,3], -1 => masked
    int kk[4][4];
    #pragma unroll
    for (int ii = 0; ii < 4; ++ii)
        #pragma unroll
        for (int jj = 0; jj < 4; ++jj)
            kk[ii][jj] = -1;
    if (active) {
        #pragma unroll
        for (int ii = 0; ii < 4; ++ii) {
            const int i = i0 + ig * 4 + ii;
            const int4 a4 = *(const int4*)(adj + ((size_t)b * NN + i) * NN + 4 * jg);
            kk[ii][0] = a4.x - 1;
            kk[ii][1] = a4.y - 1;
            kk[ii][2] = a4.z - 1;
            kk[ii][3] = a4.w - 1;
        }
    }

    // 4x4 pair tile, 4 k-accumulators each (selection deferred past the d-loop)
    float acc[4][4][4];
    #pragma unroll
    for (int ii = 0; ii < 4; ++ii)
        #pragma unroll
        for (int jj = 0; jj < 4; ++jj)
            #pragma unroll
            for (int k = 0; k < 4; ++k)
                acc[ii][jj][k] = 0.0f;

    // ---- score phase: loop d in chunks of DC=16 ----
    for (int dt = 0; dt < ND; dt += DC) {
        // stage h_j transposed, and w_k = h_i*a_k transposed
        {
            const int row = tid >> 2;            // 0..63
            const int c4  = (tid & 3) * 4;       // 0,4,8,12
            for (int j = row; j < NN; j += 64) {
                const float4 v = *(const float4*)(hb + j * ND + dt + c4);
                sHjT[c4 + 0][j] = v.x;
                sHjT[c4 + 1][j] = v.y;
                sHjT[c4 + 2][j] = v.z;
                sHjT[c4 + 3][j] = v.w;
            }
            if (row < TI) {
                const float4 hv  = *(const float4*)(hb + (i0 + row) * ND + dt + c4);
                const float4 va0 = *(const float4*)(a0 + dt + c4);
                const float4 va1 = *(const float4*)(a1 + dt + c4);
                const float4 va2 = *(const float4*)(a2 + dt + c4);
                const float4 va3 = *(const float4*)(a3 + dt + c4);
                sW[0][c4 + 0][row] = hv.x * va0.x;
                sW[0][c4 + 1][row] = hv.y * va0.y;
                sW[0][c4 + 2][row] = hv.z * va0.z;
                sW[0][c4 + 3][row] = hv.w * va0.w;
                sW[1][c4 + 0][row] = hv.x * va1.x;
                sW[1][c4 + 1][row] = hv.y * va1.y;
                sW[1][c4 + 2][row] = hv.z * va1.z;
                sW[1][c4 + 3][row] = hv.w * va1.w;
                sW[2][c4 + 0][row] = hv.x * va2.x;
                sW[2][c4 + 1][row] = hv.y * va2.y;
                sW[2][c4 + 2][row] = hv.z * va2.z;
                sW[2][c4 + 3][row] = hv.w * va2.w;
                sW[3][c4 + 0][row] = hv.x * va3.x;
                sW[3][c4 + 1][row] = hv.y * va3.y;
                sW[3][c4 + 2][row] = hv.z * va3.z;
                sW[3][c4 + 3][row] = hv.w * va3.w;
            }
        }
        __syncthreads();

        if (active) {
            #pragma unroll 4
            for (int dd = 0; dd < DC; ++dd) {
                const float4 hj4 = *(const float4*)&sHjT[dd][4 * jg];   // 1 b128
                const float hjv[4] = {hj4.x, hj4.y, hj4.z, hj4.w};
                #pragma unroll
                for (int k = 0; k < 4; ++k) {
                    const float4 w4 = *(const float4*)&sW[k][dd][4 * ig]; // 1 b128 bcast
                    const float wv_[4] = {w4.x, w4.y, w4.z, w4.w};
                    #pragma unroll
                    for (int ii = 0; ii < 4; ++ii)
                        #pragma unroll
                        for (int jj = 0; jj < 4; ++jj)
                            acc[ii][jj][k] += wv_[ii] * hjv[jj];
                }
            }
        }
        __syncthreads();
    }
    // phase-1 LDS dead from here; sS takes over the pool (barrier above).

    // ---- select k, leaky-relu, mask, write scores to LDS (float4) ----
    if (active) {
        #pragma unroll
        for (int ii = 0; ii < 4; ++ii) {
            float tmp[4];
            #pragma unroll
            for (int jj = 0; jj < 4; ++jj) {
                const int k = kk[ii][jj];
                float s = (k < 2) ? ((k == 0) ? acc[ii][jj][0] : acc[ii][jj][1])
                                  : ((k == 2) ? acc[ii][jj][2] : acc[ii][jj][3]);
                s = (s >= 0.0f) ? s : SLOPE * s;
                tmp[jj] = (k >= 0) ? s : NEG_INF;
            }
            float4 sv;
            sv.x = tmp[0]; sv.y = tmp[1]; sv.z = tmp[2]; sv.w = tmp[3];
            *(float4*)&sS[ig * 4 + ii][4 * jg] = sv;
        }
    }
    __syncthreads();

    // ---- row softmax: 4 waves x 5 rows, shuffle reduce over 64 lanes ----
    const int wv   = tid >> 6;   // 0..3
    const int lane = tid & 63;
    #pragma unroll
    for (int r = 0; r < 5; ++r) {
        const int row = wv * 5 + r;
        const float v0 = sS[row][lane];
        const float v1 = sS[row][lane + 64];
        const float v2 = sS[row][lane + 128];
        const float v3 = (lane < 8) ? sS[row][lane + 192] : NEG_INF;
        float m = fmaxf(fmaxf(v0, v1), fmaxf(v2, v3));
        #pragma unroll
        for (int off = 32; off > 0; off >>= 1)
            m = fmaxf(m, __shfl_xor(m, off, 64));
        const float p0 = __expf(v0 - m);
        const float p1 = __expf(v1 - m);
        const float p2 = __expf(v2 - m);
        const float p3 = (lane < 8) ? __expf(v3 - m) : 0.0f;
        float l = p0 + p1 + p2 + p3;
        #pragma unroll
        for (int off = 32; off > 0; off >>= 1)
            l += __shfl_xor(l, off, 64);
        const float inv = 1.0f / l;
        sS[row][lane]       = p0 * inv;
        sS[row][lane + 64]  = p1 * inv;
        sS[row][lane + 128] = p2 * inv;
        if (lane < 8) sS[row][lane + 192] = p3 * inv;
    }
    __syncthreads();

    // ---- PV: out[i][:] = sum_j alpha[i][j] * h[j][:]  (wave = 5 rows, j-quads) ----
    float o[5][4];
    #pragma unroll
    for (int r = 0; r < 5; ++r)
        #pragma unroll
        for (int c = 0; c < 4; ++c)
            o[r][c] = 0.0f;

    const int dcol = lane * 4;
    #pragma unroll 2
    for (int j4 = 0; j4 < NN / 4; ++j4) {
        float alr[5][4];
        #pragma unroll
        for (int r = 0; r < 5; ++r) {
            const float4 a4 = *(const float4*)&sS[wv * 5 + r][4 * j4]; // b128 bcast
            alr[r][0] = a4.x; alr[r][1] = a4.y; alr[r][2] = a4.z; alr[r][3] = a4.w;
        }
        #pragma unroll
        for (int q = 0; q < 4; ++q) {
            const float4 hv = *(const float4*)(hb + (size_t)(4 * j4 + q) * ND + dcol);
            #pragma unroll
            for (int r = 0; r < 5; ++r) {
                o[r][0] += alr[r][q] * hv.x;
                o[r][1] += alr[r][q] * hv.y;
                o[r][2] += alr[r][q] * hv.z;
                o[r][3] += alr[r][q] * hv.w;
            }
        }
    }

    #pragma unroll
    for (int r = 0; r < 5; ++r) {
        const int i = i0 + wv * 5 + r;
        float4 v;
        v.x = o[r][0]; v.y = o[r][1]; v.z = o[r][2]; v.w = o[r][3];
        *(float4*)(out + ((size_t)b * NN + i) * ND + dcol) = v;
    }
}

extern "C" void kernel_launch(void* const* d_in, const int* in_sizes, int n_in,
                              void* d_out, int out_size, void* d_ws, size_t ws_size,
                              hipStream_t stream) {
    const float* h   = (const float*)d_in[0];
    const int*   adj = (const int*)d_in[1];
    const float* a0  = (const float*)d_in[2];
    const float* a1  = (const float*)d_in[3];
    const float* a2  = (const float*)d_in[4];
    const float* a3  = (const float*)d_in[5];
    float* out = (float*)d_out;

    dim3 grid(NB * NTILE);   // 5120 blocks
    dim3 block(256);
    gat_w4_kernel<<<grid, block, 0, stream>>>(h, adj, a0, a1, a2, a3, out);
}